// Round 9
// baseline (100.881 us; speedup 1.0000x reference)
//
#include <hip/hip_runtime.h>

#define BATCH 4
#define NPTS  4096
#define TPB   256           // 4 waves per block
#define PPT   8             // P points per thread (register-tiled)
#define PB    (TPB * PPT)   // 2048 P points per block
#define QC    64            // Q points per LDS stage (1 KB LDS as float4)
#define ZMAX  64            // max q-chunk slices (pmin footprint 8 MB)
#define REP   2             // DIAGNOSTIC: run the scan twice so chamfer_all
                            // exceeds the 41.5us harness fills and surfaces
                            // its own counters in the top-5 profile rows.
                            // min over the same Q set is idempotent -> exact
                            // same result, absmax stays 0.

// m = min(m, a, b) in one instruction. Inputs are finite (random normals),
// so v_min3 NaN semantics vs fminf are irrelevant; guarantees 0.5 min-ops
// per distance and a short dependency chain.
__device__ __forceinline__ void min3(float& m, float a, float b) {
    asm("v_min3_f32 %0, %0, %1, %2" : "+v"(m) : "v"(a), "v"(b));
}

// One launch covers both directions: blockIdx.y = dir*BATCH + b.
// Each thread holds PPT=8 P points in registers; Q is consumed from LDS via
// wave-uniform broadcast ds_read_b128, one per Q point, amortized over 8
// distances. Per distance: 3 v_sub + 2 v_add (|.| input modifiers) +
// 0.5 v_min3 = 5.5 VALU lane-ops -> 9.4 us VALU floor per rep.
__global__ __launch_bounds__(TPB) void chamfer_all(const float* __restrict__ X,
                                                   const float* __restrict__ Y,
                                                   float* __restrict__ pmin,
                                                   float* __restrict__ out,
                                                   int zsteps, int rep) {
    // out[0] is re-poisoned before every launch; zero it here. Stream order
    // guarantees this kernel completes before reduce_loss's atomicAdds.
    if (blockIdx.x == 0 && blockIdx.y == 0 && blockIdx.z == 0 && threadIdx.x == 0)
        out[0] = 0.0f;

    const int dir = blockIdx.y >> 2;
    const int b   = blockIdx.y & 3;
    const int z   = blockIdx.z;
    const float* __restrict__ P = dir ? Y : X;
    const float* __restrict__ Q = dir ? X : Y;

    // P points in registers (12 B/lane loads, outside the hot loop)
    float px[PPT], py[PPT], pz[PPT], m[PPT];
    const int i0 = blockIdx.x * PB + threadIdx.x;
    #pragma unroll
    for (int u = 0; u < PPT; ++u) {
        const float* Pp = P + ((size_t)b * NPTS + i0 + u * TPB) * 3;
        px[u] = Pp[0];
        py[u] = Pp[1];
        pz[u] = Pp[2];
        m[u]  = __builtin_inff();
    }

    __shared__ float4 sq[QC];
    const int q0 = z * zsteps * QC;

    for (int r = 0; r < rep; ++r) {
        for (int s = 0; s < zsteps; ++s) {
            __syncthreads();   // previous stage consumed
            const float* __restrict__ Qb = Q + ((size_t)b * NPTS + q0 + s * QC) * 3;
            for (int k = threadIdx.x; k < QC; k += TPB)
                sq[k] = make_float4(Qb[3 * k], Qb[3 * k + 1], Qb[3 * k + 2], 0.0f);
            __syncthreads();

            #pragma unroll 4
            for (int j = 0; j < QC; j += 2) {
                const float4 qa = sq[j];       // broadcast ds_read_b128
                const float4 qb = sq[j + 1];
                #pragma unroll
                for (int u = 0; u < PPT; ++u) {
                    float d0 = fabsf(px[u] - qa.x) + fabsf(py[u] - qa.y) + fabsf(pz[u] - qa.z);
                    float d1 = fabsf(px[u] - qb.x) + fabsf(py[u] - qb.y) + fabsf(pz[u] - qb.z);
                    min3(m[u], d0, d1);
                }
            }
        }
    }

    float* dst = pmin + ((size_t)dir * gridDim.z + z) * (BATCH * NPTS) + b * NPTS + i0;
    #pragma unroll
    for (int u = 0; u < PPT; ++u) dst[u * TPB] = m[u];   // coalesced, no atomics
}

// pmin: [2][Z][BATCH*NPTS]. One slot per thread: min over Z (coalesced per z),
// then deterministic block sum; one atomicAdd per block into zeroed out[0].
__global__ __launch_bounds__(256) void reduce_loss(const float* __restrict__ pmin,
                                                   float* __restrict__ out, int Z) {
    const int half = BATCH * NPTS;                      // 16384 = 2^14
    const int s    = blockIdx.x * 256 + threadIdx.x;    // 0 .. 2*half-1
    const int dir  = s >> 14;
    const int idx  = s & (half - 1);

    const float* __restrict__ base = pmin + (size_t)dir * Z * half + idx;
    float v = base[0];
    for (int z = 1; z < Z; ++z) v = fminf(v, base[(size_t)z * half]);

    for (int off = 32; off > 0; off >>= 1) v += __shfl_down(v, off, 64);

    __shared__ float partial[4];
    if ((threadIdx.x & 63) == 0) partial[threadIdx.x >> 6] = v;
    __syncthreads();
    if (threadIdx.x == 0) {
        // mean(cham_x) + mean(cham_y) = (sum_x + sum_y) / (B*N)   (N == M)
        float t = (partial[0] + partial[1] + partial[2] + partial[3]) *
                  (1.0f / (float)half);
        atomicAdd(out, t);
    }
}

extern "C" void kernel_launch(void* const* d_in, const int* in_sizes, int n_in,
                              void* d_out, int out_size, void* d_ws, size_t ws_size,
                              hipStream_t stream) {
    const float* X = (const float*)d_in[0];
    const float* Y = (const float*)d_in[1];
    float* out = (float*)d_out;
    float* pmin = (float*)d_ws;

    // Largest Z whose pmin footprint (2 * Z * BATCH*NPTS floats) fits ws.
    int Z = ZMAX;
    while (Z > 1 && (size_t)2 * Z * BATCH * NPTS * sizeof(float) > ws_size) Z >>= 1;
    const int zsteps = ZMAX / Z;            // Q points per block = zsteps * QC

    dim3 grid(NPTS / PB, 2 * BATCH, Z);     // Z=64: 2 x 8 x 64 = 1024 blocks
    chamfer_all<<<grid, TPB, 0, stream>>>(X, Y, pmin, out, zsteps, REP);

    reduce_loss<<<(2 * BATCH * NPTS) / 256, 256, 0, stream>>>(pmin, out, Z);
}

// Round 11
// 82.759 us; speedup vs baseline: 1.2190x; 1.2190x over previous
//
#include <hip/hip_runtime.h>

#define BATCH 4
#define NPTS  4096
#define TPB   256           // 4 waves per block
#define PPT   8             // P points per thread (consecutive, register-tiled)
#define PB    (TPB * PPT)   // 2048 P points per block
#define QC    64            // Q points per LDS stage (1 KB LDS as float4)
#define ZMAX  64            // max q-chunk slices (pmin footprint 8 MB)

// m = min(m, a, b) in one instruction (non-volatile: schedulable, CSE-safe).
__device__ __forceinline__ void min3(float& m, float a, float b) {
    asm("v_min3_f32 %0, %0, %1, %2" : "+v"(m) : "v"(a), "v"(b));
}

// d = |a| + |b| with GUARANTEED VOP3 abs input modifiers (1 instruction).
// Discriminating experiment: if hipcc was already folding fabsf into
// modifiers this changes nothing; if it was emitting v_and_b32 per fabsf
// (8.5 ops/dist -> matches the measured 15.5us scan) this cuts to 5.5.
__device__ __forceinline__ float add_abs2(float a, float b) {
    float d;
    asm("v_add_f32 %0, |%1|, |%2|" : "=v"(d) : "v"(a), "v"(b));
    return d;
}
__device__ __forceinline__ float add_abs1(float acc, float c) {
    float d;
    asm("v_add_f32 %0, %1, |%2|" : "=v"(d) : "v"(acc), "v"(c));
    return d;
}

// One launch covers both directions: blockIdx.y = dir*BATCH + b.
// Each thread holds 8 CONSECUTIVE P points in registers (prologue = 6
// global_load_dwordx4, fully coalesced); Q consumed from LDS via wave-
// uniform broadcast ds_read_b128, 1 per Q point amortized over 8 distances.
// Per distance: 3 v_sub + 2 v_add(|.|,|.|) + 0.5 v_min3 = 5.5 VALU lane-ops.
__global__ __launch_bounds__(TPB) void chamfer_all(const float* __restrict__ X,
                                                   const float* __restrict__ Y,
                                                   float* __restrict__ pmin,
                                                   float* __restrict__ out,
                                                   int zsteps) {
    // out[0] is re-poisoned before every launch; zero it here. Stream order
    // guarantees this kernel completes before reduce_loss's atomicAdds.
    if (blockIdx.x == 0 && blockIdx.y == 0 && blockIdx.z == 0 && threadIdx.x == 0)
        out[0] = 0.0f;

    const int dir = blockIdx.y >> 2;
    const int b   = blockIdx.y & 3;
    const int z   = blockIdx.z;
    const float* __restrict__ P = dir ? Y : X;
    const float* __restrict__ Q = dir ? X : Y;

    __shared__ float4 sq[QC];
    const int q0 = z * zsteps * QC;

    // Stage-0 gather issued FIRST so its global loads overlap the P loads.
    float s0x = 0.f, s0y = 0.f, s0z = 0.f;
    {
        const float* __restrict__ Qb = Q + ((size_t)b * NPTS + q0) * 3;
        if (threadIdx.x < QC) {
            s0x = Qb[3 * threadIdx.x];
            s0y = Qb[3 * threadIdx.x + 1];
            s0z = Qb[3 * threadIdx.x + 2];
        }
    }

    // 8 consecutive P points per thread: 6 x dwordx4 (96 B/lane, coalesced).
    const int i0 = (blockIdx.x * TPB + threadIdx.x) * PPT;
    const float4* __restrict__ Psrc =
        (const float4*)(P + ((size_t)b * NPTS + i0) * 3);
    const float4 v0 = Psrc[0], v1 = Psrc[1], v2 = Psrc[2];
    const float4 v3 = Psrc[3], v4 = Psrc[4], v5 = Psrc[5];

    float px[PPT], py[PPT], pz[PPT], m[PPT];
    px[0]=v0.x; py[0]=v0.y; pz[0]=v0.z;  px[1]=v0.w; py[1]=v1.x; pz[1]=v1.y;
    px[2]=v1.z; py[2]=v1.w; pz[2]=v2.x;  px[3]=v2.y; py[3]=v2.z; pz[3]=v2.w;
    px[4]=v3.x; py[4]=v3.y; pz[4]=v3.z;  px[5]=v3.w; py[5]=v4.x; pz[5]=v4.y;
    px[6]=v4.z; py[6]=v4.w; pz[6]=v5.x;  px[7]=v5.y; py[7]=v5.z; pz[7]=v5.w;
    #pragma unroll
    for (int u = 0; u < PPT; ++u) m[u] = __builtin_inff();

    for (int s = 0; s < zsteps; ++s) {
        if (s == 0) {
            if (threadIdx.x < QC) sq[threadIdx.x] = make_float4(s0x, s0y, s0z, 0.f);
        } else {
            __syncthreads();   // previous stage consumed
            const float* __restrict__ Qb =
                Q + ((size_t)b * NPTS + q0 + s * QC) * 3;
            if (threadIdx.x < QC)
                sq[threadIdx.x] = make_float4(Qb[3 * threadIdx.x],
                                              Qb[3 * threadIdx.x + 1],
                                              Qb[3 * threadIdx.x + 2], 0.f);
        }
        __syncthreads();

        #pragma unroll 4
        for (int j = 0; j < QC; j += 2) {
            const float4 qa = sq[j];       // broadcast ds_read_b128
            const float4 qb = sq[j + 1];
            #pragma unroll
            for (int u = 0; u < PPT; ++u) {
                float a0 = px[u] - qa.x, a1 = py[u] - qa.y, a2 = pz[u] - qa.z;
                float b0 = px[u] - qb.x, b1 = py[u] - qb.y, b2 = pz[u] - qb.z;
                float d0 = add_abs1(add_abs2(a0, a1), a2);
                float d1 = add_abs1(add_abs2(b0, b1), b2);
                min3(m[u], d0, d1);
            }
        }
    }

    // 8 consecutive mins per thread: 2 x dwordx4 store (32B-aligned).
    float* dst = pmin + ((size_t)dir * gridDim.z + z) * (BATCH * NPTS) +
                 b * NPTS + i0;
    *(float4*)dst       = make_float4(m[0], m[1], m[2], m[3]);
    *((float4*)dst + 1) = make_float4(m[4], m[5], m[6], m[7]);
}

// pmin: [2][Z][BATCH*NPTS]. One slot per thread: min over Z (coalesced per z),
// then deterministic block sum; one atomicAdd per block into zeroed out[0].
__global__ __launch_bounds__(256) void reduce_loss(const float* __restrict__ pmin,
                                                   float* __restrict__ out, int Z) {
    const int half = BATCH * NPTS;                      // 16384 = 2^14
    const int s    = blockIdx.x * 256 + threadIdx.x;    // 0 .. 2*half-1
    const int dir  = s >> 14;
    const int idx  = s & (half - 1);

    const float* __restrict__ base = pmin + (size_t)dir * Z * half + idx;
    float v = base[0];
    for (int z = 1; z < Z; ++z) v = fminf(v, base[(size_t)z * half]);

    for (int off = 32; off > 0; off >>= 1) v += __shfl_down(v, off, 64);

    __shared__ float partial[4];
    if ((threadIdx.x & 63) == 0) partial[threadIdx.x >> 6] = v;
    __syncthreads();
    if (threadIdx.x == 0) {
        // mean(cham_x) + mean(cham_y) = (sum_x + sum_y) / (B*N)   (N == M)
        float t = (partial[0] + partial[1] + partial[2] + partial[3]) *
                  (1.0f / (float)half);
        atomicAdd(out, t);
    }
}

extern "C" void kernel_launch(void* const* d_in, const int* in_sizes, int n_in,
                              void* d_out, int out_size, void* d_ws, size_t ws_size,
                              hipStream_t stream) {
    const float* X = (const float*)d_in[0];
    const float* Y = (const float*)d_in[1];
    float* out = (float*)d_out;
    float* pmin = (float*)d_ws;

    // Largest Z whose pmin footprint (2 * Z * BATCH*NPTS floats) fits ws.
    int Z = ZMAX;
    while (Z > 1 && (size_t)2 * Z * BATCH * NPTS * sizeof(float) > ws_size) Z >>= 1;
    const int zsteps = ZMAX / Z;            // Q points per block = zsteps * QC

    dim3 grid(NPTS / PB, 2 * BATCH, Z);     // Z=64: 2 x 8 x 64 = 1024 blocks
    chamfer_all<<<grid, TPB, 0, stream>>>(X, Y, pmin, out, zsteps);

    reduce_loss<<<(2 * BATCH * NPTS) / 256, 256, 0, stream>>>(pmin, out, Z);
}